// Round 1
// baseline (490.072 us; speedup 1.0000x reference)
//
#include <hip/hip_runtime.h>

#define LDIM 8192
#define HDIM 16
#define DDIM 64
#define NHEADPAIR 64          // N*H
#define ROWSTRIDE 1024        // H*D floats between consecutive l for fixed h
#define KVSZ 4160             // 64*64 KV + 64 ksum
#define EPSF 1e-6f

__device__ __forceinline__ float featmap(float x) {
    // elu(x)+1 : x>0 -> x+1 ; x<=0 -> exp(x)
    return x > 0.0f ? x + 1.0f : __expf(x);
}

// ---------------- Phase 1: partial KV[d][m] and Ksum[d] per (n,h,chunk) -------------
__global__ __launch_bounds__(256) void kv_partial_kernel(
    const float* __restrict__ Kp, const float* __restrict__ Vp,
    float* __restrict__ part, int chunks, int rowsPerChunk)
{
    const int nh   = blockIdx.y;            // 0..63
    const int n    = nh >> 4;
    const int h    = nh & 15;
    const int wave = threadIdx.x >> 6;      // 0..3
    const int lane = threadIdx.x & 63;
    const int chunk = blockIdx.x * 4 + wave;
    const int d0 = (lane & 7) * 8;
    const int m0 = (lane >> 3) * 8;

    const size_t base = (((size_t)n * LDIM) * HDIM + h) * DDIM
                      + (size_t)chunk * rowsPerChunk * ROWSTRIDE;
    const float* Kb = Kp + base;
    const float* Vb = Vp + base;

    float acc[8][8];
    float ksum[8];
#pragma unroll
    for (int i = 0; i < 8; ++i) {
        ksum[i] = 0.0f;
#pragma unroll
        for (int j = 0; j < 8; ++j) acc[i][j] = 0.0f;
    }

    for (int s = 0; s < rowsPerChunk; ++s) {
        const float* kr = Kb + (size_t)s * ROWSTRIDE;
        const float* vr = Vb + (size_t)s * ROWSTRIDE;
        float4 ka = *(const float4*)(kr + d0);
        float4 kb = *(const float4*)(kr + d0 + 4);
        float4 va = *(const float4*)(vr + m0);
        float4 vb = *(const float4*)(vr + m0 + 4);
        float kf[8] = { featmap(ka.x), featmap(ka.y), featmap(ka.z), featmap(ka.w),
                        featmap(kb.x), featmap(kb.y), featmap(kb.z), featmap(kb.w) };
        float vv[8] = { va.x, va.y, va.z, va.w, vb.x, vb.y, vb.z, vb.w };
#pragma unroll
        for (int i = 0; i < 8; ++i) {
            ksum[i] += kf[i];
#pragma unroll
            for (int j = 0; j < 8; ++j) acc[i][j] += kf[i] * vv[j];
        }
    }

    float* p = part + (size_t)(nh * chunks + chunk) * KVSZ;
#pragma unroll
    for (int i = 0; i < 8; ++i) {
        float4 w0 = make_float4(acc[i][0], acc[i][1], acc[i][2], acc[i][3]);
        float4 w1 = make_float4(acc[i][4], acc[i][5], acc[i][6], acc[i][7]);
        *(float4*)(p + (d0 + i) * 64 + m0)     = w0;
        *(float4*)(p + (d0 + i) * 64 + m0 + 4) = w1;
    }
    if (m0 == 0) {
#pragma unroll
        for (int i = 0; i < 8; ++i) p[4096 + d0 + i] = ksum[i];
    }
}

// ---------------- Phase 1b: deterministic tree reduce of partials -------------------
__global__ __launch_bounds__(256) void kv_reduce_kernel(
    const float* __restrict__ part, float* __restrict__ kvf, int chunks)
{
    const int nh = blockIdx.x;
    for (int e = threadIdx.x; e < KVSZ; e += 256) {
        float s = 0.0f;
        for (int c = 0; c < chunks; ++c)
            s += part[(size_t)(nh * chunks + c) * KVSZ + e];
        kvf[(size_t)nh * KVSZ + e] = s;
    }
}

// ---------------- Phase 2: out[l][m] = Z * sum_d fm(Q[l,d]) * KV[m][d] ---------------
__global__ __launch_bounds__(256) void attn_out_kernel(
    const float* __restrict__ Qp, const float* __restrict__ kvf,
    float* __restrict__ out)
{
    __shared__ float Bt[64][64];   // Bt[d][m] = KV[m][d]  (transposed stage)
    __shared__ float ks[64];

    const int nh = blockIdx.y;
    const int n  = nh >> 4;
    const int h  = nh & 15;
    const float* kv = kvf + (size_t)nh * KVSZ;

    for (int e = threadIdx.x; e < 4096; e += 256) {
        int m = e >> 6, d = e & 63;
        Bt[d][m] = kv[e];
    }
    if (threadIdx.x < 64) ks[threadIdx.x] = kv[4096 + threadIdx.x];
    __syncthreads();

    const int wave = threadIdx.x >> 6;
    const int lane = threadIdx.x & 63;
    const int mg = lane & 7;
    const int lg = lane >> 3;
    const int m0 = mg * 8;
    const int l0 = blockIdx.x * 256 + wave * 64 + lg * 8;

    const float* Qb = Qp + (((size_t)n * LDIM) * HDIM + h) * DDIM;

    float acc[8][8];
    float zacc[8];
#pragma unroll
    for (int i = 0; i < 8; ++i) {
        zacc[i] = 0.0f;
#pragma unroll
        for (int j = 0; j < 8; ++j) acc[i][j] = 0.0f;
    }

#pragma unroll
    for (int c8 = 0; c8 < 8; ++c8) {
        const int dd = c8 * 8;
        float qf[8][8];
#pragma unroll
        for (int i = 0; i < 8; ++i) {
            const float* qr = Qb + (size_t)(l0 + i) * ROWSTRIDE + dd;
            float4 a = *(const float4*)(qr);
            float4 b = *(const float4*)(qr + 4);
            qf[i][0] = featmap(a.x); qf[i][1] = featmap(a.y);
            qf[i][2] = featmap(a.z); qf[i][3] = featmap(a.w);
            qf[i][4] = featmap(b.x); qf[i][5] = featmap(b.y);
            qf[i][6] = featmap(b.z); qf[i][7] = featmap(b.w);
        }
#pragma unroll
        for (int j = 0; j < 8; ++j) {
            const float ksj = ks[dd + j];
            float4 b0 = *(const float4*)(&Bt[dd + j][m0]);
            float4 b1 = *(const float4*)(&Bt[dd + j][m0 + 4]);
#pragma unroll
            for (int i = 0; i < 8; ++i) {
                const float q = qf[i][j];
                zacc[i]   += q * ksj;
                acc[i][0] += q * b0.x; acc[i][1] += q * b0.y;
                acc[i][2] += q * b0.z; acc[i][3] += q * b0.w;
                acc[i][4] += q * b1.x; acc[i][5] += q * b1.y;
                acc[i][6] += q * b1.z; acc[i][7] += q * b1.w;
            }
        }
    }

#pragma unroll
    for (int i = 0; i < 8; ++i) {
        const float z = 1.0f / (zacc[i] + EPSF);
        float* orow = out + (size_t)(((size_t)n * LDIM + (l0 + i)) * HDIM + h) * DDIM + m0;
        float4 w0 = make_float4(acc[i][0] * z, acc[i][1] * z, acc[i][2] * z, acc[i][3] * z);
        float4 w1 = make_float4(acc[i][4] * z, acc[i][5] * z, acc[i][6] * z, acc[i][7] * z);
        *(float4*)(orow)     = w0;
        *(float4*)(orow + 4) = w1;
    }
}

extern "C" void kernel_launch(void* const* d_in, const int* in_sizes, int n_in,
                              void* d_out, int out_size, void* d_ws, size_t ws_size,
                              hipStream_t stream) {
    const float* Q = (const float*)d_in[0];
    const float* K = (const float*)d_in[1];
    const float* V = (const float*)d_in[2];
    float* out = (float*)d_out;
    float* ws  = (float*)d_ws;

    // pick chunk count (per head-pair) that fits the workspace
    int chunks = 32;
    while (chunks > 4 &&
           (size_t)(NHEADPAIR * chunks + NHEADPAIR) * KVSZ * sizeof(float) > ws_size)
        chunks >>= 1;
    const int rowsPerChunk = LDIM / chunks;

    float* part = ws;
    float* kvf  = ws + (size_t)NHEADPAIR * chunks * KVSZ;

    dim3 g1(chunks / 4, NHEADPAIR);
    kv_partial_kernel<<<g1, 256, 0, stream>>>(K, V, part, chunks, rowsPerChunk);
    kv_reduce_kernel<<<NHEADPAIR, 256, 0, stream>>>(part, kvf, chunks);
    dim3 g2(LDIM / 256, NHEADPAIR);
    attn_out_kernel<<<g2, 256, 0, stream>>>(Q, kvf, out);
}

// Round 2
// 278.256 us; speedup vs baseline: 1.7612x; 1.7612x over previous
//
#include <hip/hip_runtime.h>

#define LDIM 8192
#define HDIM 16
#define DDIM 64
#define NHEADPAIR 64          // N*H
#define ROWSTRIDE 1024        // H*D floats between consecutive l for fixed h
#define KVSZ 4160             // 64*64 KV + 64 ksum
#define EPSF 1e-6f

__device__ __forceinline__ float featmap(float x) {
    // elu(x)+1 : x>0 -> x+1 ; x<=0 -> exp(x)
    return x > 0.0f ? x + 1.0f : __expf(x);
}

// ---------------- Phase 1: partial KV[d][m] and Ksum[d] per (n,h,chunk) -------------
__global__ __launch_bounds__(256) void kv_partial_kernel(
    const float* __restrict__ Kp, const float* __restrict__ Vp,
    float* __restrict__ part, int chunks, int rowsPerChunk)
{
    const int nh   = blockIdx.y;            // 0..63
    const int n    = nh >> 4;
    const int h    = nh & 15;
    const int wave = threadIdx.x >> 6;      // 0..3
    const int lane = threadIdx.x & 63;
    const int chunk = blockIdx.x * 4 + wave;
    const int d0 = (lane & 7) * 8;
    const int m0 = (lane >> 3) * 8;

    const size_t base = (((size_t)n * LDIM) * HDIM + h) * DDIM
                      + (size_t)chunk * rowsPerChunk * ROWSTRIDE;
    const float* Kb = Kp + base;
    const float* Vb = Vp + base;

    float acc[8][8];
    float ksum[8];
#pragma unroll
    for (int i = 0; i < 8; ++i) {
        ksum[i] = 0.0f;
#pragma unroll
        for (int j = 0; j < 8; ++j) acc[i][j] = 0.0f;
    }

    // software pipeline: keep next row's loads in flight during FMA
    float4 ka0 = *(const float4*)(Kb + d0);
    float4 kb0 = *(const float4*)(Kb + d0 + 4);
    float4 va0 = *(const float4*)(Vb + m0);
    float4 vb0 = *(const float4*)(Vb + m0 + 4);

    for (int s = 0; s < rowsPerChunk; ++s) {
        const int sn = (s + 1 < rowsPerChunk) ? s + 1 : s;
        const float* krn = Kb + (size_t)sn * ROWSTRIDE;
        const float* vrn = Vb + (size_t)sn * ROWSTRIDE;
        float4 ka1 = *(const float4*)(krn + d0);
        float4 kb1 = *(const float4*)(krn + d0 + 4);
        float4 va1 = *(const float4*)(vrn + m0);
        float4 vb1 = *(const float4*)(vrn + m0 + 4);

        float kf[8] = { featmap(ka0.x), featmap(ka0.y), featmap(ka0.z), featmap(ka0.w),
                        featmap(kb0.x), featmap(kb0.y), featmap(kb0.z), featmap(kb0.w) };
        float vv[8] = { va0.x, va0.y, va0.z, va0.w, vb0.x, vb0.y, vb0.z, vb0.w };
#pragma unroll
        for (int i = 0; i < 8; ++i) {
            ksum[i] += kf[i];
#pragma unroll
            for (int j = 0; j < 8; ++j) acc[i][j] += kf[i] * vv[j];
        }
        ka0 = ka1; kb0 = kb1; va0 = va1; vb0 = vb1;
    }

    float* p = part + (size_t)(nh * chunks + chunk) * KVSZ;
#pragma unroll
    for (int i = 0; i < 8; ++i) {
        float4 w0 = make_float4(acc[i][0], acc[i][1], acc[i][2], acc[i][3]);
        float4 w1 = make_float4(acc[i][4], acc[i][5], acc[i][6], acc[i][7]);
        *(float4*)(p + (d0 + i) * 64 + m0)     = w0;
        *(float4*)(p + (d0 + i) * 64 + m0 + 4) = w1;
    }
    if (m0 == 0) {
#pragma unroll
        for (int i = 0; i < 8; ++i) p[4096 + d0 + i] = ksum[i];
    }
}

// ---------------- Phase 1b: deterministic parallel reduce of partials ---------------
__global__ __launch_bounds__(256) void kv_reduce_kernel(
    const float* __restrict__ part, float* __restrict__ kvf, int chunks)
{
    const int nh = blockIdx.y;
    const int e  = blockIdx.x * 256 + threadIdx.x;
    if (e >= KVSZ) return;
    float s = 0.0f;
    for (int c = 0; c < chunks; ++c)
        s += part[(size_t)(nh * chunks + c) * KVSZ + e];
    kvf[(size_t)nh * KVSZ + e] = s;
}

// ---------------- Phase 2: out[l][m] = Z * sum_d fm(Q[l,d]) * KV[m][d] ---------------
__global__ __launch_bounds__(256) void attn_out_kernel(
    const float* __restrict__ Qp, const float* __restrict__ kvf,
    float* __restrict__ out)
{
    __shared__ float Bt[64][68];   // Bt[d][m] = KV[m][d]; pad 68 keeps b128 rows 16B-aligned
    __shared__ float ks[64];

    const int nh = blockIdx.y;
    const int n  = nh >> 4;
    const int h  = nh & 15;
    const float* kv = kvf + (size_t)nh * KVSZ;

    for (int e = threadIdx.x; e < 4096; e += 256) {
        int m = e >> 6, d = e & 63;
        Bt[d][m] = kv[e];
    }
    if (threadIdx.x < 64) ks[threadIdx.x] = kv[4096 + threadIdx.x];
    __syncthreads();

    const int wave = threadIdx.x >> 6;
    const int lane = threadIdx.x & 63;
    const int mg = lane & 7;
    const int lg = lane >> 3;
    const int m0 = mg * 8;
    const int l0 = blockIdx.x * 128 + wave * 32 + lg * 4;   // 4 rows per thread

    const float* Qb = Qp + (((size_t)n * LDIM) * HDIM + h) * DDIM;

    float acc[4][8];
    float zacc[4];
#pragma unroll
    for (int i = 0; i < 4; ++i) {
        zacc[i] = 0.0f;
#pragma unroll
        for (int j = 0; j < 8; ++j) acc[i][j] = 0.0f;
    }

#pragma unroll
    for (int c8 = 0; c8 < 8; ++c8) {
        const int dd = c8 * 8;
        float qf[4][8];
#pragma unroll
        for (int i = 0; i < 4; ++i) {
            const float* qr = Qb + (size_t)(l0 + i) * ROWSTRIDE + dd;
            float4 a = *(const float4*)(qr);
            float4 b = *(const float4*)(qr + 4);
            qf[i][0] = featmap(a.x); qf[i][1] = featmap(a.y);
            qf[i][2] = featmap(a.z); qf[i][3] = featmap(a.w);
            qf[i][4] = featmap(b.x); qf[i][5] = featmap(b.y);
            qf[i][6] = featmap(b.z); qf[i][7] = featmap(b.w);
        }
#pragma unroll
        for (int j = 0; j < 8; ++j) {
            const float ksj = ks[dd + j];
            float4 b0 = *(const float4*)(&Bt[dd + j][m0]);
            float4 b1 = *(const float4*)(&Bt[dd + j][m0 + 4]);
#pragma unroll
            for (int i = 0; i < 4; ++i) {
                const float q = qf[i][j];
                zacc[i]   += q * ksj;
                acc[i][0] += q * b0.x; acc[i][1] += q * b0.y;
                acc[i][2] += q * b0.z; acc[i][3] += q * b0.w;
                acc[i][4] += q * b1.x; acc[i][5] += q * b1.y;
                acc[i][6] += q * b1.z; acc[i][7] += q * b1.w;
            }
        }
    }

#pragma unroll
    for (int i = 0; i < 4; ++i) {
        const float z = 1.0f / (zacc[i] + EPSF);
        float* orow = out + (((size_t)n * LDIM + (l0 + i)) * HDIM + h) * DDIM + m0;
        float4 w0 = make_float4(acc[i][0] * z, acc[i][1] * z, acc[i][2] * z, acc[i][3] * z);
        float4 w1 = make_float4(acc[i][4] * z, acc[i][5] * z, acc[i][6] * z, acc[i][7] * z);
        *(float4*)(orow)     = w0;
        *(float4*)(orow + 4) = w1;
    }
}

extern "C" void kernel_launch(void* const* d_in, const int* in_sizes, int n_in,
                              void* d_out, int out_size, void* d_ws, size_t ws_size,
                              hipStream_t stream) {
    const float* Q = (const float*)d_in[0];
    const float* K = (const float*)d_in[1];
    const float* V = (const float*)d_in[2];
    float* out = (float*)d_out;
    float* ws  = (float*)d_ws;

    // pick chunk count (per head-pair) that fits the workspace
    int chunks = 64;
    while (chunks > 4 &&
           ((size_t)NHEADPAIR * chunks + NHEADPAIR) * KVSZ * sizeof(float) > ws_size)
        chunks >>= 1;
    const int rowsPerChunk = LDIM / chunks;

    float* part = ws;
    float* kvf  = ws + (size_t)NHEADPAIR * chunks * KVSZ;

    dim3 g1(chunks / 4, NHEADPAIR);
    kv_partial_kernel<<<g1, 256, 0, stream>>>(K, V, part, chunks, rowsPerChunk);
    dim3 gr((KVSZ + 255) / 256, NHEADPAIR);
    kv_reduce_kernel<<<gr, 256, 0, stream>>>(part, kvf, chunks);
    dim3 g2(LDIM / 128, NHEADPAIR);
    attn_out_kernel<<<g2, 256, 0, stream>>>(Q, kvf, out);
}

// Round 3
// 260.649 us; speedup vs baseline: 1.8802x; 1.0675x over previous
//
#include <hip/hip_runtime.h>

#define LDIM 8192
#define HDIM 16
#define DDIM 64
#define NHEADPAIR 64          // N*H
#define ROWSTRIDE 1024        // H*D floats between consecutive l for fixed h
#define KVSZ 4160             // 64*64 KV + 64 ksum
#define EPSF 1e-6f
#define SROWS 16              // rows staged per LDS group
#define LPAD 68               // padded LDS row (breaks 256B bank wrap on stage writes)

__device__ __forceinline__ float featmap(float x) {
    // elu(x)+1 : x>0 -> x+1 ; x<=0 -> exp(x)
    return x > 0.0f ? x + 1.0f : __expf(x);
}

__device__ __forceinline__ float4 fm4(float4 a) {
    return make_float4(featmap(a.x), featmap(a.y), featmap(a.z), featmap(a.w));
}

// ---------------- Phase 1: partial KV[d][m] and Ksum[d] per (n,h,chunk) -------------
// Block-cooperative: 256 threads share one chunk; K,V staged via LDS (featmap once).
__global__ __launch_bounds__(256) void kv_partial_kernel(
    const float* __restrict__ Kp, const float* __restrict__ Vp,
    float* __restrict__ part, int chunks, int rowsPerChunk)
{
    __shared__ float Kf[2][SROWS][LPAD];
    __shared__ float Vf[2][SROWS][LPAD];

    const int nh    = blockIdx.y;           // 0..63
    const int n     = nh >> 4;
    const int h     = nh & 15;
    const int chunk = blockIdx.x;
    const int t     = threadIdx.x;

    // staging map: thread -> (row in group, 4-col)
    const int sr = t >> 4;                  // 0..15
    const int sc = (t & 15) * 4;            // 0,4,..,60
    // compute map: thread -> 4x4 (d,m) tile
    const int d0 = (t & 15) * 4;
    const int m0 = (t >> 4) * 4;

    const size_t base = (((size_t)n * LDIM) * HDIM + h) * DDIM
                      + (size_t)chunk * rowsPerChunk * ROWSTRIDE;
    const float* Kb = Kp + base;
    const float* Vb = Vp + base;
    const int NG = rowsPerChunk / SROWS;

    float acc[4][4];
    float ksum[4];
#pragma unroll
    for (int i = 0; i < 4; ++i) {
        ksum[i] = 0.0f;
#pragma unroll
        for (int j = 0; j < 4; ++j) acc[i][j] = 0.0f;
    }

    // prologue: stage group 0
    {
        float4 kr = *(const float4*)(Kb + (size_t)sr * ROWSTRIDE + sc);
        float4 vr = *(const float4*)(Vb + (size_t)sr * ROWSTRIDE + sc);
        *(float4*)&Kf[0][sr][sc] = fm4(kr);
        *(float4*)&Vf[0][sr][sc] = vr;
    }
    __syncthreads();

    for (int g = 0; g < NG; ++g) {
        float4 krn, vrn;
        const bool more = (g + 1 < NG);
        if (more) {
            const float* kp = Kb + ((size_t)(g + 1) * SROWS + sr) * ROWSTRIDE + sc;
            const float* vp = Vb + ((size_t)(g + 1) * SROWS + sr) * ROWSTRIDE + sc;
            krn = *(const float4*)kp;       // in flight during compute below
            vrn = *(const float4*)vp;
        }

        const int cb = g & 1;
#pragma unroll
        for (int r = 0; r < SROWS; ++r) {
            float4 kq = *(const float4*)&Kf[cb][r][d0];
            float4 vq = *(const float4*)&Vf[cb][r][m0];
            float kk[4] = { kq.x, kq.y, kq.z, kq.w };
            float vv[4] = { vq.x, vq.y, vq.z, vq.w };
#pragma unroll
            for (int i = 0; i < 4; ++i) {
                ksum[i] += kk[i];
#pragma unroll
                for (int j = 0; j < 4; ++j) acc[i][j] += kk[i] * vv[j];
            }
        }

        if (more) {
            *(float4*)&Kf[cb ^ 1][sr][sc] = fm4(krn);
            *(float4*)&Vf[cb ^ 1][sr][sc] = vrn;
        }
        __syncthreads();
    }

    float* p = part + (size_t)(nh * chunks + chunk) * KVSZ;
#pragma unroll
    for (int i = 0; i < 4; ++i) {
        *(float4*)(p + (d0 + i) * 64 + m0) =
            make_float4(acc[i][0], acc[i][1], acc[i][2], acc[i][3]);
    }
    if (m0 == 0) {
#pragma unroll
        for (int i = 0; i < 4; ++i) p[4096 + d0 + i] = ksum[i];
    }
}

// ---------------- Phase 1b: deterministic parallel reduce of partials ---------------
__global__ __launch_bounds__(256) void kv_reduce_kernel(
    const float* __restrict__ part, float* __restrict__ kvf, int chunks)
{
    const int nh = blockIdx.y;
    const int e  = blockIdx.x * 256 + threadIdx.x;
    if (e >= KVSZ) return;
    float s = 0.0f;
    for (int c = 0; c < chunks; ++c)
        s += part[(size_t)(nh * chunks + c) * KVSZ + e];
    kvf[(size_t)nh * KVSZ + e] = s;
}

// ---------------- Phase 2: out[l][m] = Z * sum_d fm(Q[l,d]) * KV[m][d] ---------------
__global__ __launch_bounds__(256) void attn_out_kernel(
    const float* __restrict__ Qp, const float* __restrict__ kvf,
    float* __restrict__ out)
{
    __shared__ float Bt[64][68];   // Bt[d][m] = KV[m][d]; pad keeps banks spread
    __shared__ float ks[64];

    const int nh = blockIdx.y;
    const int n  = nh >> 4;
    const int h  = nh & 15;
    const float* kv = kvf + (size_t)nh * KVSZ;

    for (int e = threadIdx.x; e < 4096; e += 256) {
        int m = e >> 6, d = e & 63;
        Bt[d][m] = kv[e];
    }
    if (threadIdx.x < 64) ks[threadIdx.x] = kv[4096 + threadIdx.x];
    __syncthreads();

    const int wave = threadIdx.x >> 6;
    const int lane = threadIdx.x & 63;
    const int mg = lane & 7;
    const int lg = lane >> 3;
    const int m0 = mg * 8;
    const int l0 = blockIdx.x * 64 + wave * 16 + lg * 2;   // 2 rows per thread

    const float* Qb = Qp + (((size_t)n * LDIM) * HDIM + h) * DDIM;

    float acc[2][8];
    float zacc[2];
#pragma unroll
    for (int i = 0; i < 2; ++i) {
        zacc[i] = 0.0f;
#pragma unroll
        for (int j = 0; j < 8; ++j) acc[i][j] = 0.0f;
    }

#pragma unroll
    for (int c8 = 0; c8 < 8; ++c8) {
        const int dd = c8 * 8;
        float qf[2][8];
#pragma unroll
        for (int i = 0; i < 2; ++i) {
            const float* qr = Qb + (size_t)(l0 + i) * ROWSTRIDE + dd;
            float4 a = *(const float4*)(qr);
            float4 b = *(const float4*)(qr + 4);
            qf[i][0] = featmap(a.x); qf[i][1] = featmap(a.y);
            qf[i][2] = featmap(a.z); qf[i][3] = featmap(a.w);
            qf[i][4] = featmap(b.x); qf[i][5] = featmap(b.y);
            qf[i][6] = featmap(b.z); qf[i][7] = featmap(b.w);
        }
#pragma unroll
        for (int j = 0; j < 8; ++j) {
            const float ksj = ks[dd + j];
            float4 b0 = *(const float4*)(&Bt[dd + j][m0]);
            float4 b1 = *(const float4*)(&Bt[dd + j][m0 + 4]);
#pragma unroll
            for (int i = 0; i < 2; ++i) {
                const float q = qf[i][j];
                zacc[i]   += q * ksj;
                acc[i][0] += q * b0.x; acc[i][1] += q * b0.y;
                acc[i][2] += q * b0.z; acc[i][3] += q * b0.w;
                acc[i][4] += q * b1.x; acc[i][5] += q * b1.y;
                acc[i][6] += q * b1.z; acc[i][7] += q * b1.w;
            }
        }
    }

#pragma unroll
    for (int i = 0; i < 2; ++i) {
        const float z = 1.0f / (zacc[i] + EPSF);
        float* orow = out + (((size_t)n * LDIM + (l0 + i)) * HDIM + h) * DDIM + m0;
        *(float4*)(orow)     = make_float4(acc[i][0] * z, acc[i][1] * z,
                                           acc[i][2] * z, acc[i][3] * z);
        *(float4*)(orow + 4) = make_float4(acc[i][4] * z, acc[i][5] * z,
                                           acc[i][6] * z, acc[i][7] * z);
    }
}

extern "C" void kernel_launch(void* const* d_in, const int* in_sizes, int n_in,
                              void* d_out, int out_size, void* d_ws, size_t ws_size,
                              hipStream_t stream) {
    const float* Q = (const float*)d_in[0];
    const float* K = (const float*)d_in[1];
    const float* V = (const float*)d_in[2];
    float* out = (float*)d_out;
    float* ws  = (float*)d_ws;

    // pick chunk count (per head-pair) that fits the workspace
    int chunks = 64;
    while (chunks > 4 &&
           ((size_t)NHEADPAIR * chunks + NHEADPAIR) * KVSZ * sizeof(float) > ws_size)
        chunks >>= 1;
    const int rowsPerChunk = LDIM / chunks;

    float* part = ws;
    float* kvf  = ws + (size_t)NHEADPAIR * chunks * KVSZ;

    dim3 g1(chunks, NHEADPAIR);
    kv_partial_kernel<<<g1, 256, 0, stream>>>(K, V, part, chunks, rowsPerChunk);
    dim3 gr((KVSZ + 255) / 256, NHEADPAIR);
    kv_reduce_kernel<<<gr, 256, 0, stream>>>(part, kvf, chunks);
    dim3 g2(LDIM / 64, NHEADPAIR);
    attn_out_kernel<<<g2, 256, 0, stream>>>(Q, kvf, out);
}